// Round 12
// baseline (346.511 us; speedup 1.0000x reference)
//
#include <hip/hip_runtime.h>
#include <stdint.h>

// ---------------------------------------------------------------------------
// MultiHeadAttention: B=8 S=1024 QKV=1024 H=16 E=64 OUT=1024.
// fp32 in / fp32 out, bf16 MFMA internals, fp32 accum.
// R19: revert R18 (interleaved thirds tripled FETCH 57->171MB: mixed q/k/v
//   working sets overflowed per-XCD L2; prep/cvt merge also suspect) and
//   apply the R16-verified occupancy lever to proj3 instead:
//   BN=64 for ALL proj thirds -> 48KB LDS -> 3 blocks/CU (was 64KB -> 2).
//   Grid 3072, CONTIGUOUS thirds (third=id>>10), XCD-chunked within third
//   (bx=(local>>3)&15, by=8*(local>>7)+(local&7)) — R17 locality restored.
//   v third: BN=64 fp32-A core (As72 18KB + Bs 8KB), acc[4][2].
// R17 kept: V^T global layout + all-DMA dbuf flash staging; separate
//   prep_wt3/cvt3. R16: gemm_out BN=64. R15: native casts + setprio.
// R14: T2 swizzle. R13: counted-vmcnt pipe. R12: XCD decode.
// flash MFMA maps (HW-verified m89/m91):
//   A[m=lane&15][k=quad*8+j], B[k=quad*8+j][n=lane&15], D[row=quad*4+r][col]
// ws: [Qp 16][Kp 16][VpT 16][WqT 2|WkT 2|WvT 2|WoB 2] = 56 MB.
// d_out doubles as bf16 scratch (q~ at 0, k~ at 16MB).
// ---------------------------------------------------------------------------

typedef __bf16 bf16x8 __attribute__((ext_vector_type(8)));
typedef float f32x4 __attribute__((ext_vector_type(4)));

typedef __attribute__((address_space(3))) uint32_t lds_u32;
typedef const __attribute__((address_space(1))) uint32_t glb_u32;

// Native cast -> compiler emits v_cvt_pk_bf16_f32 (RNE), packing pairs.
__device__ __forceinline__ ushort f2bf(float f) {
  union { __bf16 b; ushort u; } c;
  c.b = (__bf16)f;
  return c.u;
}
__device__ __forceinline__ bf16x8 ld8(const ushort* p) {
  union { uint4 u; bf16x8 b; } c;
  c.u = *reinterpret_cast<const uint4*>(p);
  return c.b;
}
__device__ __forceinline__ void cvt16(const float* __restrict__ src,
                                      ushort* __restrict__ dst) {
  union { uint4 u[2]; ushort s[16]; } o;
#pragma unroll
  for (int i = 0; i < 4; ++i) {
    const float4 f = reinterpret_cast<const float4*>(src)[i];
    o.s[4 * i + 0] = f2bf(f.x);
    o.s[4 * i + 1] = f2bf(f.y);
    o.s[4 * i + 2] = f2bf(f.z);
    o.s[4 * i + 3] = f2bf(f.w);
  }
  reinterpret_cast<uint4*>(dst)[0] = o.u[0];
  reinterpret_cast<uint4*>(dst)[1] = o.u[1];
}

// global->LDS DMA, 16B/lane. LDS dest wave-uniform base + lane*16 (m104/m108).
__device__ __forceinline__ void gld16(const ushort* g, ushort* l) {
  __builtin_amdgcn_global_load_lds((glb_u32*)g, (lds_u32*)l, 16, 0, 0);
}

// --------------------------------------------------------------------------
// W[16][1024][64] fp32 -> WT[1024][1024] bf16 (WT[n=h*64+e][k]).
// 3 weights in one launch: grid 768 (bid>>8 selects W). 256 thr.
// --------------------------------------------------------------------------
__global__ __launch_bounds__(256) void prep_wt3(
    const float* __restrict__ W0, const float* __restrict__ W1,
    const float* __restrict__ W2, ushort* __restrict__ T0,
    ushort* __restrict__ T1, ushort* __restrict__ T2) {
  __shared__ __align__(16) ushort tile[64 * 72];
  const int sel = blockIdx.x >> 8;
  const float* W = sel == 0 ? W0 : sel == 1 ? W1 : W2;
  ushort* WT = sel == 0 ? T0 : sel == 1 ? T1 : T2;
  const int bid = blockIdx.x & 255;
  const int h = bid >> 4;
  const int kt = bid & 15;
  const int t = threadIdx.x;
  const int row = t >> 2;
  const int ch = (t & 3) * 16;
  cvt16(W + ((size_t)h * 1024 + kt * 64 + row) * 64 + ch, &tile[row * 72 + ch]);
  __syncthreads();
  const int e = t >> 2;
  const int kc = (t & 3) * 16;
  ushort vals[16];
#pragma unroll
  for (int j = 0; j < 16; ++j) vals[j] = tile[(kc + j) * 72 + e];
  ushort* dst = WT + (size_t)(h * 64 + e) * 1024 + kt * 64 + kc;
  reinterpret_cast<uint4*>(dst)[0] = *reinterpret_cast<uint4*>(&vals[0]);
  reinterpret_cast<uint4*>(dst)[1] = *reinterpret_cast<uint4*>(&vals[8]);
}

// q (8M) + k (8M) + Wo (1M) fp32->bf16 in one launch. grid 4352.
__global__ __launch_bounds__(256) void cvt3(const float* __restrict__ s0,
                                            ushort* __restrict__ d0,
                                            const float* __restrict__ s1,
                                            ushort* __restrict__ d1,
                                            const float* __restrict__ s2,
                                            ushort* __restrict__ d2) {
  int b = blockIdx.x;
  const float* s;
  ushort* d;
  if (b < 2048) { s = s0; d = d0; }
  else if (b < 4096) { s = s1; d = d1; b -= 2048; }
  else { s = s2; d = d2; b -= 4096; }
  const int i = (b * 256 + threadIdx.x) * 16;
  cvt16(s + i, d + i);
}

// --------------------------------------------------------------------------
// Pipelined GEMM core (bf16 A): counted-vmcnt double-buffer + T2 swizzle.
// BM=128 fixed, BN templated (128 or 64). 4 waves 2x2; wave tile 64 x BN/2.
// --------------------------------------------------------------------------
template <bool F32OUT, int BN>
__device__ __forceinline__ void core_bb_pipe(ushort* __restrict__ S,
                                             const ushort* __restrict__ A,
                                             const ushort* __restrict__ Bt,
                                             const float* __restrict__ bias,
                                             void* __restrict__ Cv,
                                             float oscale, int bx, int by) {
  constexpr int JN = BN / 32;       // acc N-fragments per wave (4 or 2)
  constexpr int BLOADS = BN / 32;   // B staging loads per wave (4 or 2)
  constexpr int WN = BN / 2;        // wave N stride
  ushort* A0 = S;
  ushort* B0 = S + 128 * 64;
  ushort* A1 = S + 128 * 64 + BN * 64;
  ushort* B1 = S + 2 * 128 * 64 + BN * 64;
  const int n0 = bx * BN;
  const int m0 = by * 128;
  const int t = threadIdx.x;
  const int lane = t & 63;
  const int w = t >> 6;
  const int wm = w >> 1, wn = w & 1;
  const int col = lane & 15;
  const int quad = lane >> 4;
  const int gr = lane >> 3;                    // 0..7 (row within 8-row chunk)
  const int gc = ((lane & 7) ^ gr) * 8;        // SWIZZLED source granule
  const int s7 = col & 7;                      // read-side row parity

  f32x4 acc[4][JN];
#pragma unroll
  for (int i = 0; i < 4; ++i)
#pragma unroll
    for (int j = 0; j < JN; ++j) acc[i][j] = (f32x4){0.f, 0.f, 0.f, 0.f};

  const ushort* a_src = A + (size_t)(m0 + w * 8 + gr) * 1024 + gc;
  const ushort* b_src = Bt + (size_t)(n0 + w * 8 + gr) * 1024 + gc;

  auto stage = [&](ushort* as, ushort* bs, int k0) {
#pragma unroll
    for (int c = 0; c < 4; ++c)
      gld16(a_src + (size_t)c * 32 * 1024 + k0, as + (w * 8 + c * 32) * 64);
#pragma unroll
    for (int c = 0; c < BLOADS; ++c)
      gld16(b_src + (size_t)c * 32 * 1024 + k0, bs + (w * 8 + c * 32) * 64);
  };
  auto wait_prev = [&]() {
    if constexpr (BN == 128)
      asm volatile("s_waitcnt vmcnt(8)" ::: "memory");
    else
      asm volatile("s_waitcnt vmcnt(6)" ::: "memory");
  };

  auto compute = [&](const ushort* asb, const ushort* bsb) {
#pragma unroll
    for (int half = 0; half < 2; ++half) {
      bf16x8 af[4], bfr[JN];
      const int g0 = half * 4 + quad;          // logical granule of this read
      const int gs = (g0 ^ s7) << 3;           // swizzled LDS offset (ushorts)
#pragma unroll
      for (int i = 0; i < 4; ++i)
        af[i] = ld8(&asb[(wm * 64 + i * 16 + col) * 64 + gs]);
#pragma unroll
      for (int j = 0; j < JN; ++j)
        bfr[j] = ld8(&bsb[(wn * WN + j * 16 + col) * 64 + gs]);
#pragma unroll
      for (int i = 0; i < 4; ++i)
#pragma unroll
        for (int j = 0; j < JN; ++j)
          acc[i][j] = __builtin_amdgcn_mfma_f32_16x16x32_bf16(af[i], bfr[j],
                                                              acc[i][j], 0, 0, 0);
    }
  };

  // prologue: tile 0 -> buf0 (loads in flight)
  stage(A0, B0, 0);

  for (int t2 = 0; t2 < 16; t2 += 2) {
    // even step: read buf0, stage t2+1 -> buf1
    stage(A1, B1, (t2 + 1) * 64);
    wait_prev();
    __builtin_amdgcn_sched_barrier(0);
    __builtin_amdgcn_s_barrier();
    __builtin_amdgcn_sched_barrier(0);
    compute(A0, B0);
    asm volatile("s_waitcnt lgkmcnt(0)" ::: "memory");  // my reads retired
    __builtin_amdgcn_sched_barrier(0);
    __builtin_amdgcn_s_barrier();

    // odd step: read buf1, stage t2+2 -> buf0 (skip on last)
    if (t2 < 14) {
      stage(A0, B0, (t2 + 2) * 64);
      wait_prev();
    } else {
      asm volatile("s_waitcnt vmcnt(0)" ::: "memory");
    }
    __builtin_amdgcn_sched_barrier(0);
    __builtin_amdgcn_s_barrier();
    __builtin_amdgcn_sched_barrier(0);
    compute(A1, B1);
    asm volatile("s_waitcnt lgkmcnt(0)" ::: "memory");
    __builtin_amdgcn_sched_barrier(0);
    __builtin_amdgcn_s_barrier();
  }

#pragma unroll
  for (int i = 0; i < 4; ++i)
#pragma unroll
    for (int j = 0; j < JN; ++j) {
      const int n = n0 + wn * WN + j * 16 + col;
      float bv = 0.f;
      if (F32OUT) bv = bias[n];
#pragma unroll
      for (int r = 0; r < 4; ++r) {
        const int m = m0 + wm * 64 + i * 16 + quad * 4 + r;
        if (F32OUT)
          reinterpret_cast<float*>(Cv)[(size_t)m * 1024 + n] = acc[i][j][r] + bv;
        else
          reinterpret_cast<ushort*>(Cv)[(size_t)m * 1024 + n] =
              f2bf(acc[i][j][r] * oscale);
      }
    }
}

// --------------------------------------------------------------------------
// V-projection core, BN=64 (fp32 A, in-kernel cvt): A staged via cvt16 into
// stride-72 LDS (R7-verified), B (64 rows) via gld16 + T2 swizzle.
// Single-buffer. OUTPUT TRANSPOSED: Ct[n][m], n=h*64+e, m=b*1024+s,
// packed 8B stores. Uses S[0..13312) of the 48KB pool. acc[4][2].
// --------------------------------------------------------------------------
__device__ __forceinline__ void core_f32a64_T(ushort* __restrict__ S,
                                              const float* __restrict__ A,
                                              const ushort* __restrict__ Bt,
                                              ushort* __restrict__ Ct, int bx,
                                              int by) {
  ushort* As72 = S;                 // 128*72
  ushort* Bs = S + 128 * 72;        // 64*64
  const int n0 = bx * 64;
  const int m0 = by * 128;
  const int t = threadIdx.x;
  const int lane = t & 63;
  const int w = t >> 6;
  const int wm = w >> 1, wn = w & 1;
  const int col = lane & 15;
  const int quad = lane >> 4;
  const int gr = lane >> 3;
  const int gc = ((lane & 7) ^ gr) * 8;        // SWIZZLED source granule (B)
  const int s7 = col & 7;
  const int srow = t >> 1;        // 0..127
  const int sc0 = (t & 1) * 32;   // 0 or 32

  f32x4 acc[4][2];
#pragma unroll
  for (int i = 0; i < 4; ++i)
#pragma unroll
    for (int j = 0; j < 2; ++j) acc[i][j] = (f32x4){0.f, 0.f, 0.f, 0.f};

  const float* a_src = A + (size_t)(m0 + srow) * 1024 + sc0;
  const ushort* b_src = Bt + (size_t)(n0 + w * 8 + gr) * 1024 + gc;

  for (int k0 = 0; k0 < 1024; k0 += 64) {
#pragma unroll
    for (int c = 0; c < 2; ++c)
      gld16(b_src + (size_t)c * 32 * 1024 + k0, Bs + (w * 8 + c * 32) * 64);
    cvt16(a_src + k0, &As72[srow * 72 + sc0]);
    cvt16(a_src + k0 + 16, &As72[srow * 72 + sc0 + 16]);
    __syncthreads();

#pragma unroll
    for (int half = 0; half < 2; ++half) {
      bf16x8 af[4], bfr[2];
      const int gs = ((half * 4 + quad) ^ s7) << 3;
#pragma unroll
      for (int i = 0; i < 4; ++i)
        af[i] = ld8(&As72[(wm * 64 + i * 16 + col) * 72 + half * 32 + quad * 8]);
#pragma unroll
      for (int j = 0; j < 2; ++j)
        bfr[j] = ld8(&Bs[(wn * 32 + j * 16 + col) * 64 + gs]);
#pragma unroll
      for (int i = 0; i < 4; ++i)
#pragma unroll
        for (int j = 0; j < 2; ++j)
          acc[i][j] = __builtin_amdgcn_mfma_f32_16x16x32_bf16(af[i], bfr[j],
                                                              acc[i][j], 0, 0, 0);
    }
    __syncthreads();
  }

  // transposed epilogue: Ct[n][m], 4 consecutive m packed per 8B store
#pragma unroll
  for (int i = 0; i < 4; ++i)
#pragma unroll
    for (int j = 0; j < 2; ++j) {
      const int n = n0 + wn * 32 + j * 16 + col;
      const int mb = m0 + wm * 64 + i * 16 + quad * 4;
      union { uint2 u; ushort s[4]; } pk;
#pragma unroll
      for (int r = 0; r < 4; ++r) pk.s[r] = f2bf(acc[i][j][r]);
      *reinterpret_cast<uint2*>(&Ct[(size_t)n * 8192 + mb]) = pk.u;
    }
}

// OUT gemm: C fp32 + bias. BN=64: grid 1024 (64x16 tiles), 3 blocks/CU.
// Decode: bx=(id>>3)&15, by=8*(id>>7)+(id&7) — bijective; same-A-panel
// blocks (16 bx) share an XCD (id%8) and are dispatch-adjacent.
__global__ __launch_bounds__(256) void gemm_out(const ushort* __restrict__ A,
                                                const ushort* __restrict__ Bt,
                                                const float* __restrict__ bias,
                                                float* __restrict__ C) {
  __shared__ __align__(16) ushort S[2 * 128 * 64 + 2 * 64 * 64];  // 48KB
  const int id = blockIdx.x;
  const int bx = (id >> 3) & 15;
  const int by = ((id >> 7) << 3) | (id & 7);
  core_bb_pipe<true, 64>(S, A, Bt, bias, C, 1.0f, bx, by);
}

// All three projections in one launch, grid 3072, BN=64, 48KB LDS (3/CU).
// CONTIGUOUS thirds: third = id>>10 (0=q,1=k,2=v); local = id & 1023;
// bx = (local>>3)&15 (0..15), by = 8*(local>>7)+(local&7) (0..63).
// Same-A-panel 16-bx group = contiguous 128-id chunk on one XCD (id%8).
__global__ __launch_bounds__(256) void gemm_proj3(
    const ushort* __restrict__ Aq, const ushort* __restrict__ Bq,
    ushort* __restrict__ Cq, const ushort* __restrict__ Ak,
    const ushort* __restrict__ Bk, ushort* __restrict__ Ck,
    const float* __restrict__ Av, const ushort* __restrict__ Bv,
    ushort* __restrict__ Cvt) {
  __shared__ __align__(16) ushort S[2 * 128 * 64 + 2 * 64 * 64];  // 48KB
  const int id = blockIdx.x;
  const int third = id >> 10;
  const int local = id & 1023;
  const int bx = (local >> 3) & 15;
  const int by = ((local >> 7) << 3) | (local & 7);
  if (third == 0)
    core_bb_pipe<false, 64>(S, Aq, Bq, nullptr, Cq, 0.03125f, bx, by);
  else if (third == 1)
    core_bb_pipe<false, 64>(S, Ak, Bk, nullptr, Ck, 1.0f, bx, by);
  else
    core_f32a64_T(S, Av, Bv, Cvt, bx, by);
}

// --------------------------------------------------------------------------
// Flash attention, 128-row q-tiles. Q,K,O bf16 [8192][1024]; VT bf16
// [1024][8192] (V transposed). O aliases Q. Q PRE-SCALED by 1/sqrt(1024).
// grid 1024; block 256 (4 waves); wave w owns q-rows w*32..+31.
// Swapped QK^T (lane-local softmax rows). Defer-max THR=8.
// K AND V staged via gld16 + granule-XOR swizzle, double-buffered with
// counted vmcnt. LDS 50KB (3/CU). UNCHANGED from R17 (control).
// --------------------------------------------------------------------------
__global__ __launch_bounds__(256) void flash_attn(const ushort* __restrict__ Q,
                                                  const ushort* __restrict__ K,
                                                  const ushort* __restrict__ VT,
                                                  ushort* __restrict__ O) {
  __shared__ __align__(16) ushort QP[128 * 72];
  __shared__ __align__(16) ushort Ks0[64 * 64];
  __shared__ __align__(16) ushort Ks1[64 * 64];
  __shared__ __align__(16) ushort Vt0[64 * 64];
  __shared__ __align__(16) ushort Vt1[64 * 64];
  const int pair = blockIdx.x & 127;
  const int b = pair >> 4;
  const int h = pair & 15;
  const int qt = blockIdx.x >> 7;
  const int t = threadIdx.x;
  const int lane = t & 63;
  const int w = t >> 6;
  const int col = lane & 15;
  const int quad = lane >> 4;

  const size_t base = (size_t)b * 1024 * 1024 + h * 64;
  const int qrow0 = qt * 128;

  // stage Q (128 x 64): 32 ushorts per thread
  {
    const int row = t >> 1;
    const int c0 = (t & 1) * 32;
    const ushort* src = Q + base + (size_t)(qrow0 + row) * 1024 + c0;
    uint4 v0 = reinterpret_cast<const uint4*>(src)[0];
    uint4 v1 = reinterpret_cast<const uint4*>(src)[1];
    uint4 v2 = reinterpret_cast<const uint4*>(src)[2];
    uint4 v3 = reinterpret_cast<const uint4*>(src)[3];
    reinterpret_cast<uint4*>(&QP[row * 72 + c0])[0] = v0;
    reinterpret_cast<uint4*>(&QP[row * 72 + c0])[1] = v1;
    reinterpret_cast<uint4*>(&QP[row * 72 + c0])[2] = v2;
    reinterpret_cast<uint4*>(&QP[row * 72 + c0])[3] = v3;
  }
  __syncthreads();
  bf16x8 qa[2][2];
#pragma unroll
  for (int g = 0; g < 2; ++g)
#pragma unroll
    for (int half = 0; half < 2; ++half)
      qa[g][half] =
          ld8(&QP[(w * 32 + g * 16 + col) * 72 + half * 32 + quad * 8]);

  f32x4 o_[2][4];
#pragma unroll
  for (int g = 0; g < 2; ++g)
#pragma unroll
    for (int c = 0; c < 4; ++c) o_[g][c] = (f32x4){0.f, 0.f, 0.f, 0.f};
  float m_s[2] = {-1e30f, -1e30f};
  float l_s[2] = {0.f, 0.f};

  // staging geometry (swizzled gld16): wave w covers rows w*16..w*16+15
  const int gr = lane >> 3;
  const int kcs = (((lane & 7) ^ gr) << 3);  // swizzled granule (ushorts)
  const int s7 = col & 7;
  const ushort* krowp = K + base + (size_t)(w * 16 + gr) * 1024 + kcs;
  const ushort* vrowp =
      VT + (size_t)(h * 64 + w * 16 + gr) * 8192 + (size_t)b * 1024 + kcs;

  auto stageKV = [&](ushort* kb, ushort* vb, int kt) {
    const ushort* k0 = krowp + (size_t)kt * 64 * 1024;
    gld16(k0, kb + (w * 16) * 64);
    gld16(k0 + (size_t)8 * 1024, kb + (w * 16 + 8) * 64);
    const ushort* v0 = vrowp + kt * 64;
    gld16(v0, vb + (w * 16) * 64);
    gld16(v0 + (size_t)8 * 8192, vb + (w * 16 + 8) * 64);
  };

  auto body = [&](const ushort* kb, const ushort* vb) {
    // S^T = K Q^T; sc[g][c][r] = S[q=lane&15(+g*16+w*32)][k=c*16+quad*4+r]
    f32x4 sc[2][4];
    __builtin_amdgcn_s_setprio(1);
#pragma unroll
    for (int c = 0; c < 4; ++c) {
      const int R = (c * 16 + col) * 64;
      bf16x8 kb0 = ld8(&kb[R + ((quad ^ s7) << 3)]);
      bf16x8 kb1 = ld8(&kb[R + (((quad + 4) ^ s7) << 3)]);
#pragma unroll
      for (int g = 0; g < 2; ++g) {
        f32x4 z = {0.f, 0.f, 0.f, 0.f};
        z = __builtin_amdgcn_mfma_f32_16x16x32_bf16(kb0, qa[g][0], z, 0, 0, 0);
        z = __builtin_amdgcn_mfma_f32_16x16x32_bf16(kb1, qa[g][1], z, 0, 0, 0);
        sc[g][c] = z;
      }
    }
    __builtin_amdgcn_s_setprio(0);

    // online softmax, row-local, with defer-max (THR=8)
    float al[2];
    bool df[2];
#pragma unroll
    for (int g = 0; g < 2; ++g) {
      float mx = sc[g][0][0];
#pragma unroll
      for (int c = 0; c < 4; ++c)
#pragma unroll
        for (int r = 0; r < 4; ++r) mx = fmaxf(mx, sc[g][c][r]);
      mx = fmaxf(mx, __shfl_xor(mx, 16));
      mx = fmaxf(mx, __shfl_xor(mx, 32));
      df[g] = __all(mx - m_s[g] <= 8.0f) != 0;
      if (df[g]) {
        al[g] = 1.0f;
      } else {
        const float m_new = fmaxf(m_s[g], mx);
        al[g] = __expf(m_s[g] - m_new);
        m_s[g] = m_new;
      }
      float rs = 0.f;
      const int prow = (w * 32 + g * 16 + col) * 72;
#pragma unroll
      for (int c = 0; c < 4; ++c) {
        const float p0 = __expf(sc[g][c][0] - m_s[g]);
        const float p1 = __expf(sc[g][c][1] - m_s[g]);
        const float p2 = __expf(sc[g][c][2] - m_s[g]);
        const float p3 = __expf(sc[g][c][3] - m_s[g]);
        rs += (p0 + p1) + (p2 + p3);
        union { uint2 u; ushort s[4]; } pk;
        pk.s[0] = f2bf(p0);
        pk.s[1] = f2bf(p1);
        pk.s[2] = f2bf(p2);
        pk.s[3] = f2bf(p3);
        *reinterpret_cast<uint2*>(&QP[prow + c * 16 + quad * 4]) = pk.u;
      }
      rs += __shfl_xor(rs, 16);
      rs += __shfl_xor(rs, 32);
      l_s[g] = df[g] ? (l_s[g] + rs) : (l_s[g] * al[g] + rs);
    }

    // rescale O with per-row alpha (skipped entirely when deferred)
#pragma unroll
    for (int g = 0; g < 2; ++g)
      if (!df[g]) {
#pragma unroll
        for (int r = 0; r < 4; ++r) {
          const float a = __shfl(al[g], (lane & 48) | (quad * 4 + r));
          o_[g][0][r] *= a;
          o_[g][1][r] *= a;
          o_[g][2][r] *= a;
          o_[g][3][r] *= a;
        }
      }

    // O += P V (own-wave P rows; in-wave DS order suffices)
    bf16x8 pa[2][2];
#pragma unroll
    for (int g = 0; g < 2; ++g)
#pragma unroll
      for (int half = 0; half < 2; ++half)
        pa[g][half] =
            ld8(&QP[(w * 32 + g * 16 + col) * 72 + half * 32 + quad * 8]);
    __builtin_amdgcn_s_setprio(1);
#pragma unroll
    for (int c = 0; c < 4; ++c) {
      const int R = (c * 16 + col) * 64;
      bf16x8 vb0 = ld8(&vb[R + ((quad ^ s7) << 3)]);
      bf16x8 vb1 = ld8(&vb[R + (((quad + 4) ^ s7) << 3)]);
#pragma unroll
      for (int g = 0; g < 2; ++g) {
        o_[g][c] = __builtin_amdgcn_mfma_f32_16x16x32_bf16(pa[g][0], vb0,
                                                           o_[g][c], 0, 0, 0);
        o_[g][c] = __builtin_amdgcn_mfma_f32_16x16x32_bf16(pa[g][1], vb1,
                                                           o_[g][c], 0, 0, 0);
      }
    }
    __builtin_amdgcn_s_setprio(0);
  };

  // prologue: stage tile 0, full drain (also completes qa reads before any
  // wave can write P into QP -> race-free)
  stageKV(Ks0, Vt0, 0);
  __syncthreads();

  for (int t2 = 0; t2 < 16; t2 += 2) {
    // even step: compute buf0, stage t2+1 -> buf1 (t2+1 <= 15 always)
    stageKV(Ks1, Vt1, t2 + 1);
    asm volatile("s_waitcnt vmcnt(4)" ::: "memory");
    __builtin_amdgcn_sched_barrier(0);
    __builtin_amdgcn_s_barrier();
    __builtin_amdgcn_sched_barrier(0);
    body(Ks0, Vt0);
    asm volatile("s_waitcnt lgkmcnt(0)" ::: "memory");
    __builtin_amdgcn_sched_barrier(0);
    __builtin_amdgcn_s_barrier();

    // odd step: compute buf1, stage t2+2 -> buf0 (skip on last)
    if (t2 < 14) {
      stageKV(Ks0, Vt0, t2 + 2);
      asm volatile("s_waitcnt vmcnt(4)" ::: "memory");
    } else {
      asm volatile("s_waitcnt vmcnt(0)" ::: "memory");
    }
    __builtin_amdgcn_sched_barrier(0);
    __builtin_amdgcn_s_barrier();
    __builtin_amdgcn_sched_barrier(0);
    body(Ks1, Vt1);
    asm volatile("s_waitcnt lgkmcnt(0)" ::: "memory");
    __builtin_amdgcn_sched_barrier(0);
    __builtin_amdgcn_s_barrier();
  }

#pragma unroll
  for (int g = 0; g < 2; ++g)
#pragma unroll
    for (int r = 0; r < 4; ++r) {
      const float lr = __shfl(l_s[g], (lane & 48) | (quad * 4 + r));
      const float inv = 1.f / lr;
      const size_t row =
          base + (size_t)(qrow0 + w * 32 + g * 16 + quad * 4 + r) * 1024;
      O[row + 0 + col] = f2bf(o_[g][0][r] * inv);
      O[row + 16 + col] = f2bf(o_[g][1][r] * inv);
      O[row + 32 + col] = f2bf(o_[g][2][r] * inv);
      O[row + 48 + col] = f2bf(o_[g][3][r] * inv);
    }
}

// --------------------------------------------------------------------------
extern "C" void kernel_launch(void* const* d_in, const int* in_sizes, int n_in,
                              void* d_out, int out_size, void* d_ws, size_t ws_size,
                              hipStream_t stream) {
  const float* q = (const float*)d_in[0];
  const float* k = (const float*)d_in[1];
  const float* v = (const float*)d_in[2];
  const float* Wq = (const float*)d_in[3];
  const float* Wk = (const float*)d_in[4];
  const float* Wv = (const float*)d_in[5];
  const float* Wo = (const float*)d_in[6];
  const float* bo = (const float*)d_in[7];
  float* out = (float*)d_out;
  ushort* ws = (ushort*)d_ws;

  const size_t M8 = 8u << 20;  // 8M bf16 = 16 MB
  const size_t M1 = 1u << 20;
  ushort* Qp = ws;                 // also flash output (in-place)
  ushort* Kp = ws + M8;
  ushort* VpT = ws + 2 * M8;       // V TRANSPOSED [1024][8192]
  ushort* WqT = ws + 3 * M8;
  ushort* WkT = WqT + M1;
  ushort* WvT = WkT + M1;
  ushort* WoB = WvT + M1;          // total 56 MB

  // d_out (32 MB fp32) as bf16 scratch: q~ at 0, k~ at +16MB.
  ushort* X0 = (ushort*)d_out;
  ushort* X1 = X0 + M8;

  prep_wt3<<<768, 256, 0, stream>>>(Wq, Wk, Wv, WqT, WkT, WvT);
  cvt3<<<4352, 256, 0, stream>>>(q, X0, k, X1, Wo, WoB);
  // attn scale folded into Q projection (exact: 2^-5 exponent shift in bf16)
  gemm_proj3<<<3072, 256, 0, stream>>>(X0, WqT, Qp, X1, WkT, Kp, v, WvT, VpT);

  flash_attn<<<1024, 256, 0, stream>>>(Qp, Kp, VpT, Qp);

  gemm_out<<<1024, 256, 0, stream>>>(Qp, WoB, bo, out);
}

// Round 13
// 312.508 us; speedup vs baseline: 1.1088x; 1.1088x over previous
//
#include <hip/hip_runtime.h>
#include <stdint.h>

// ---------------------------------------------------------------------------
// MultiHeadAttention: B=8 S=1024 QKV=1024 H=16 E=64 OUT=1024.
// fp32 in / fp32 out, bf16 MFMA internals, fp32 accum.
// R20: exact R17 revert (312.6us best; R18 interleave broke L2 locality
//   FETCH 57->171MB, R19 BN=64 proj3 halved pipeline cover 114->125us)
//   + ONE change: proj3 thirds dispatch V FIRST (grp=(id>>9): 0=v,1=q,2=k).
//   The single-buffer v third is slowest; in R17 it formed the whole tail
//   cohort at 2 blocks/CU. v-first overlaps v with pipelined q/k and makes
//   the tail fast-k. Same per-block code, same XCD locality (id%8 fixed
//   within a panel group), zero numerics change.
// R17: V^T global layout + all-DMA dbuf flash staging. R16: gemm_out BN=64.
// R15: native casts + setprio. R14: T2 swizzle. R13: counted-vmcnt pipe.
// R12: XCD decode.
// flash MFMA maps (HW-verified m89/m91):
//   A[m=lane&15][k=quad*8+j], B[k=quad*8+j][n=lane&15], D[row=quad*4+r][col]
// ws: [Qp 16][Kp 16][VpT 16][WqT 2|WkT 2|WvT 2|WoB 2] = 56 MB.
// d_out doubles as bf16 scratch (q~ at 0, k~ at 16MB).
// ---------------------------------------------------------------------------

typedef __bf16 bf16x8 __attribute__((ext_vector_type(8)));
typedef float f32x4 __attribute__((ext_vector_type(4)));

typedef __attribute__((address_space(3))) uint32_t lds_u32;
typedef const __attribute__((address_space(1))) uint32_t glb_u32;

// Native cast -> compiler emits v_cvt_pk_bf16_f32 (RNE), packing pairs.
__device__ __forceinline__ ushort f2bf(float f) {
  union { __bf16 b; ushort u; } c;
  c.b = (__bf16)f;
  return c.u;
}
__device__ __forceinline__ bf16x8 ld8(const ushort* p) {
  union { uint4 u; bf16x8 b; } c;
  c.u = *reinterpret_cast<const uint4*>(p);
  return c.b;
}
__device__ __forceinline__ void cvt16(const float* __restrict__ src,
                                      ushort* __restrict__ dst) {
  union { uint4 u[2]; ushort s[16]; } o;
#pragma unroll
  for (int i = 0; i < 4; ++i) {
    const float4 f = reinterpret_cast<const float4*>(src)[i];
    o.s[4 * i + 0] = f2bf(f.x);
    o.s[4 * i + 1] = f2bf(f.y);
    o.s[4 * i + 2] = f2bf(f.z);
    o.s[4 * i + 3] = f2bf(f.w);
  }
  reinterpret_cast<uint4*>(dst)[0] = o.u[0];
  reinterpret_cast<uint4*>(dst)[1] = o.u[1];
}

// global->LDS DMA, 16B/lane. LDS dest wave-uniform base + lane*16 (m104/m108).
__device__ __forceinline__ void gld16(const ushort* g, ushort* l) {
  __builtin_amdgcn_global_load_lds((glb_u32*)g, (lds_u32*)l, 16, 0, 0);
}

// --------------------------------------------------------------------------
// W[16][1024][64] fp32 -> WT[1024][1024] bf16 (WT[n=h*64+e][k]).
// 3 weights in one launch: grid 768 (bid>>8 selects W). 256 thr.
// --------------------------------------------------------------------------
__global__ __launch_bounds__(256) void prep_wt3(
    const float* __restrict__ W0, const float* __restrict__ W1,
    const float* __restrict__ W2, ushort* __restrict__ T0,
    ushort* __restrict__ T1, ushort* __restrict__ T2) {
  __shared__ __align__(16) ushort tile[64 * 72];
  const int sel = blockIdx.x >> 8;
  const float* W = sel == 0 ? W0 : sel == 1 ? W1 : W2;
  ushort* WT = sel == 0 ? T0 : sel == 1 ? T1 : T2;
  const int bid = blockIdx.x & 255;
  const int h = bid >> 4;
  const int kt = bid & 15;
  const int t = threadIdx.x;
  const int row = t >> 2;
  const int ch = (t & 3) * 16;
  cvt16(W + ((size_t)h * 1024 + kt * 64 + row) * 64 + ch, &tile[row * 72 + ch]);
  __syncthreads();
  const int e = t >> 2;
  const int kc = (t & 3) * 16;
  ushort vals[16];
#pragma unroll
  for (int j = 0; j < 16; ++j) vals[j] = tile[(kc + j) * 72 + e];
  ushort* dst = WT + (size_t)(h * 64 + e) * 1024 + kt * 64 + kc;
  reinterpret_cast<uint4*>(dst)[0] = *reinterpret_cast<uint4*>(&vals[0]);
  reinterpret_cast<uint4*>(dst)[1] = *reinterpret_cast<uint4*>(&vals[8]);
}

// q (8M) + k (8M) + Wo (1M) fp32->bf16 in one launch. grid 4352.
__global__ __launch_bounds__(256) void cvt3(const float* __restrict__ s0,
                                            ushort* __restrict__ d0,
                                            const float* __restrict__ s1,
                                            ushort* __restrict__ d1,
                                            const float* __restrict__ s2,
                                            ushort* __restrict__ d2) {
  int b = blockIdx.x;
  const float* s;
  ushort* d;
  if (b < 2048) { s = s0; d = d0; }
  else if (b < 4096) { s = s1; d = d1; b -= 2048; }
  else { s = s2; d = d2; b -= 4096; }
  const int i = (b * 256 + threadIdx.x) * 16;
  cvt16(s + i, d + i);
}

// --------------------------------------------------------------------------
// Pipelined GEMM core (bf16 A): counted-vmcnt double-buffer + T2 swizzle.
// BM=128 fixed, BN templated (128 or 64). 4 waves 2x2; wave tile 64 x BN/2.
// --------------------------------------------------------------------------
template <bool F32OUT, int BN>
__device__ __forceinline__ void core_bb_pipe(ushort* __restrict__ S,
                                             const ushort* __restrict__ A,
                                             const ushort* __restrict__ Bt,
                                             const float* __restrict__ bias,
                                             void* __restrict__ Cv,
                                             float oscale, int bx, int by) {
  constexpr int JN = BN / 32;       // acc N-fragments per wave (4 or 2)
  constexpr int BLOADS = BN / 32;   // B staging loads per wave (4 or 2)
  constexpr int WN = BN / 2;        // wave N stride
  ushort* A0 = S;
  ushort* B0 = S + 128 * 64;
  ushort* A1 = S + 128 * 64 + BN * 64;
  ushort* B1 = S + 2 * 128 * 64 + BN * 64;
  const int n0 = bx * BN;
  const int m0 = by * 128;
  const int t = threadIdx.x;
  const int lane = t & 63;
  const int w = t >> 6;
  const int wm = w >> 1, wn = w & 1;
  const int col = lane & 15;
  const int quad = lane >> 4;
  const int gr = lane >> 3;                    // 0..7 (row within 8-row chunk)
  const int gc = ((lane & 7) ^ gr) * 8;        // SWIZZLED source granule
  const int s7 = col & 7;                      // read-side row parity

  f32x4 acc[4][JN];
#pragma unroll
  for (int i = 0; i < 4; ++i)
#pragma unroll
    for (int j = 0; j < JN; ++j) acc[i][j] = (f32x4){0.f, 0.f, 0.f, 0.f};

  const ushort* a_src = A + (size_t)(m0 + w * 8 + gr) * 1024 + gc;
  const ushort* b_src = Bt + (size_t)(n0 + w * 8 + gr) * 1024 + gc;

  auto stage = [&](ushort* as, ushort* bs, int k0) {
#pragma unroll
    for (int c = 0; c < 4; ++c)
      gld16(a_src + (size_t)c * 32 * 1024 + k0, as + (w * 8 + c * 32) * 64);
#pragma unroll
    for (int c = 0; c < BLOADS; ++c)
      gld16(b_src + (size_t)c * 32 * 1024 + k0, bs + (w * 8 + c * 32) * 64);
  };
  auto wait_prev = [&]() {
    if constexpr (BN == 128)
      asm volatile("s_waitcnt vmcnt(8)" ::: "memory");
    else
      asm volatile("s_waitcnt vmcnt(6)" ::: "memory");
  };

  auto compute = [&](const ushort* asb, const ushort* bsb) {
#pragma unroll
    for (int half = 0; half < 2; ++half) {
      bf16x8 af[4], bfr[JN];
      const int g0 = half * 4 + quad;          // logical granule of this read
      const int gs = (g0 ^ s7) << 3;           // swizzled LDS offset (ushorts)
#pragma unroll
      for (int i = 0; i < 4; ++i)
        af[i] = ld8(&asb[(wm * 64 + i * 16 + col) * 64 + gs]);
#pragma unroll
      for (int j = 0; j < JN; ++j)
        bfr[j] = ld8(&bsb[(wn * WN + j * 16 + col) * 64 + gs]);
#pragma unroll
      for (int i = 0; i < 4; ++i)
#pragma unroll
        for (int j = 0; j < JN; ++j)
          acc[i][j] = __builtin_amdgcn_mfma_f32_16x16x32_bf16(af[i], bfr[j],
                                                              acc[i][j], 0, 0, 0);
    }
  };

  // prologue: tile 0 -> buf0 (loads in flight)
  stage(A0, B0, 0);

  for (int t2 = 0; t2 < 16; t2 += 2) {
    // even step: read buf0, stage t2+1 -> buf1
    stage(A1, B1, (t2 + 1) * 64);
    wait_prev();
    __builtin_amdgcn_sched_barrier(0);
    __builtin_amdgcn_s_barrier();
    __builtin_amdgcn_sched_barrier(0);
    compute(A0, B0);
    asm volatile("s_waitcnt lgkmcnt(0)" ::: "memory");  // my reads retired
    __builtin_amdgcn_sched_barrier(0);
    __builtin_amdgcn_s_barrier();

    // odd step: read buf1, stage t2+2 -> buf0 (skip on last)
    if (t2 < 14) {
      stage(A0, B0, (t2 + 2) * 64);
      wait_prev();
    } else {
      asm volatile("s_waitcnt vmcnt(0)" ::: "memory");
    }
    __builtin_amdgcn_sched_barrier(0);
    __builtin_amdgcn_s_barrier();
    __builtin_amdgcn_sched_barrier(0);
    compute(A1, B1);
    asm volatile("s_waitcnt lgkmcnt(0)" ::: "memory");
    __builtin_amdgcn_sched_barrier(0);
    __builtin_amdgcn_s_barrier();
  }

#pragma unroll
  for (int i = 0; i < 4; ++i)
#pragma unroll
    for (int j = 0; j < JN; ++j) {
      const int n = n0 + wn * WN + j * 16 + col;
      float bv = 0.f;
      if (F32OUT) bv = bias[n];
#pragma unroll
      for (int r = 0; r < 4; ++r) {
        const int m = m0 + wm * 64 + i * 16 + quad * 4 + r;
        if (F32OUT)
          reinterpret_cast<float*>(Cv)[(size_t)m * 1024 + n] = acc[i][j][r] + bv;
        else
          reinterpret_cast<ushort*>(Cv)[(size_t)m * 1024 + n] =
              f2bf(acc[i][j][r] * oscale);
      }
    }
}

// --------------------------------------------------------------------------
// V-projection core (fp32 A, in-kernel cvt): A staged via cvt16 into
// stride-72 LDS (R7-verified), B via gld16 + T2 swizzle. Single-buffer.
// OUTPUT IS TRANSPOSED: Ct[n][m], n=h*64+e, m=b*1024+s — packed 8B stores.
// --------------------------------------------------------------------------
__device__ __forceinline__ void core_f32a_T(ushort* __restrict__ S,
                                            const float* __restrict__ A,
                                            const ushort* __restrict__ Bt,
                                            ushort* __restrict__ Ct, int bx,
                                            int by) {
  ushort* As72 = S;                 // 128*72
  ushort* Bs = S + 128 * 72;        // 128*64
  const int n0 = bx * 128;
  const int m0 = by * 128;
  const int t = threadIdx.x;
  const int lane = t & 63;
  const int w = t >> 6;
  const int wm = w >> 1, wn = w & 1;
  const int col = lane & 15;
  const int quad = lane >> 4;
  const int gr = lane >> 3;
  const int gc = ((lane & 7) ^ gr) * 8;        // SWIZZLED source granule (B)
  const int s7 = col & 7;
  const int srow = t >> 1;        // 0..127
  const int sc0 = (t & 1) * 32;   // 0 or 32

  f32x4 acc[4][4];
#pragma unroll
  for (int i = 0; i < 4; ++i)
#pragma unroll
    for (int j = 0; j < 4; ++j) acc[i][j] = (f32x4){0.f, 0.f, 0.f, 0.f};

  const float* a_src = A + (size_t)(m0 + srow) * 1024 + sc0;
  const ushort* b_src = Bt + (size_t)(n0 + w * 8 + gr) * 1024 + gc;
  ushort* bs_base = &Bs[(w * 8) * 64];

  for (int k0 = 0; k0 < 1024; k0 += 64) {
#pragma unroll
    for (int c = 0; c < 4; ++c)
      gld16(b_src + (size_t)c * 32 * 1024 + k0, bs_base + c * 32 * 64);
    cvt16(a_src + k0, &As72[srow * 72 + sc0]);
    cvt16(a_src + k0 + 16, &As72[srow * 72 + sc0 + 16]);
    __syncthreads();

#pragma unroll
    for (int half = 0; half < 2; ++half) {
      bf16x8 af[4], bfr[4];
      const int gs = ((half * 4 + quad) ^ s7) << 3;
#pragma unroll
      for (int i = 0; i < 4; ++i)
        af[i] = ld8(&As72[(wm * 64 + i * 16 + col) * 72 + half * 32 + quad * 8]);
#pragma unroll
      for (int j = 0; j < 4; ++j)
        bfr[j] = ld8(&Bs[(wn * 64 + j * 16 + col) * 64 + gs]);
#pragma unroll
      for (int i = 0; i < 4; ++i)
#pragma unroll
        for (int j = 0; j < 4; ++j)
          acc[i][j] = __builtin_amdgcn_mfma_f32_16x16x32_bf16(af[i], bfr[j],
                                                              acc[i][j], 0, 0, 0);
    }
    __syncthreads();
  }

  // transposed epilogue: Ct[n][m], 4 consecutive m packed per 8B store
#pragma unroll
  for (int i = 0; i < 4; ++i)
#pragma unroll
    for (int j = 0; j < 4; ++j) {
      const int n = n0 + wn * 64 + j * 16 + col;
      const int mb = m0 + wm * 64 + i * 16 + quad * 4;
      union { uint2 u; ushort s[4]; } pk;
#pragma unroll
      for (int r = 0; r < 4; ++r) pk.s[r] = f2bf(acc[i][j][r]);
      *reinterpret_cast<uint2*>(&Ct[(size_t)n * 8192 + mb]) = pk.u;
    }
}

// OUT gemm: C fp32 + bias. BN=64: grid 1024 (64x16 tiles), 3 blocks/CU.
// Decode: bx=(id>>3)&15, by=8*(id>>7)+(id&7) — bijective; same-A-panel
// blocks (16 bx) share an XCD (id%8) and are dispatch-adjacent.
__global__ __launch_bounds__(256) void gemm_out(const ushort* __restrict__ A,
                                                const ushort* __restrict__ Bt,
                                                const float* __restrict__ bias,
                                                float* __restrict__ C) {
  __shared__ __align__(16) ushort S[2 * 128 * 64 + 2 * 64 * 64];  // 48KB
  const int id = blockIdx.x;
  const int bx = (id >> 3) & 15;
  const int by = ((id >> 7) << 3) | (id & 7);
  core_bb_pipe<true, 64>(S, A, Bt, bias, C, 1.0f, bx, by);
}

// All three projections in one launch. grid 1536 (1D, XCD-chunked decode).
// id: a=id>>6 (0..23), bx=(id>>3)&7, b=id&7; by=(a&7)*8+b (0..63).
// grp = a>>3: 0 -> V (single-buffer, slowest, dispatched FIRST so it
// overlaps with pipelined q/k instead of forming the tail), 1 -> q, 2 -> k.
// Same-A-panel 8-bx group: same a,b -> same XCD (id%8=b), adjacent ids.
__global__ __launch_bounds__(256) void gemm_proj3(
    const ushort* __restrict__ Aq, const ushort* __restrict__ Bq,
    ushort* __restrict__ Cq, const ushort* __restrict__ Ak,
    const ushort* __restrict__ Bk, ushort* __restrict__ Ck,
    const float* __restrict__ Av, const ushort* __restrict__ Bv,
    ushort* __restrict__ Cvt) {
  __shared__ __align__(16) ushort S[4 * 128 * 64];  // 64KB shared pool
  const int id = blockIdx.x;
  const int bx = (id >> 3) & 7;
  const int a = id >> 6;
  const int grp = a >> 3;
  const int by = ((a & 7) << 3) | (id & 7);
  if (grp == 0)
    core_f32a_T(S, Av, Bv, Cvt, bx, by);
  else if (grp == 1)
    core_bb_pipe<false, 128>(S, Aq, Bq, nullptr, Cq, 0.03125f, bx, by);
  else
    core_bb_pipe<false, 128>(S, Ak, Bk, nullptr, Ck, 1.0f, bx, by);
}

// --------------------------------------------------------------------------
// Flash attention, 128-row q-tiles. Q,K,O bf16 [8192][1024]; VT bf16
// [1024][8192] (V transposed). O aliases Q. Q PRE-SCALED by 1/sqrt(1024).
// grid 1024; block 256 (4 waves); wave w owns q-rows w*32..+31.
// Swapped QK^T (lane-local softmax rows). Defer-max THR=8.
// K AND V staged via gld16 + granule-XOR swizzle, double-buffered with
// counted vmcnt. LDS 50KB (3/CU). UNCHANGED from R17 (control).
// --------------------------------------------------------------------------
__global__ __launch_bounds__(256) void flash_attn(const ushort* __restrict__ Q,
                                                  const ushort* __restrict__ K,
                                                  const ushort* __restrict__ VT,
                                                  ushort* __restrict__ O) {
  __shared__ __align__(16) ushort QP[128 * 72];
  __shared__ __align__(16) ushort Ks0[64 * 64];
  __shared__ __align__(16) ushort Ks1[64 * 64];
  __shared__ __align__(16) ushort Vt0[64 * 64];
  __shared__ __align__(16) ushort Vt1[64 * 64];
  const int pair = blockIdx.x & 127;
  const int b = pair >> 4;
  const int h = pair & 15;
  const int qt = blockIdx.x >> 7;
  const int t = threadIdx.x;
  const int lane = t & 63;
  const int w = t >> 6;
  const int col = lane & 15;
  const int quad = lane >> 4;

  const size_t base = (size_t)b * 1024 * 1024 + h * 64;
  const int qrow0 = qt * 128;

  // stage Q (128 x 64): 32 ushorts per thread
  {
    const int row = t >> 1;
    const int c0 = (t & 1) * 32;
    const ushort* src = Q + base + (size_t)(qrow0 + row) * 1024 + c0;
    uint4 v0 = reinterpret_cast<const uint4*>(src)[0];
    uint4 v1 = reinterpret_cast<const uint4*>(src)[1];
    uint4 v2 = reinterpret_cast<const uint4*>(src)[2];
    uint4 v3 = reinterpret_cast<const uint4*>(src)[3];
    reinterpret_cast<uint4*>(&QP[row * 72 + c0])[0] = v0;
    reinterpret_cast<uint4*>(&QP[row * 72 + c0])[1] = v1;
    reinterpret_cast<uint4*>(&QP[row * 72 + c0])[2] = v2;
    reinterpret_cast<uint4*>(&QP[row * 72 + c0])[3] = v3;
  }
  __syncthreads();
  bf16x8 qa[2][2];
#pragma unroll
  for (int g = 0; g < 2; ++g)
#pragma unroll
    for (int half = 0; half < 2; ++half)
      qa[g][half] =
          ld8(&QP[(w * 32 + g * 16 + col) * 72 + half * 32 + quad * 8]);

  f32x4 o_[2][4];
#pragma unroll
  for (int g = 0; g < 2; ++g)
#pragma unroll
    for (int c = 0; c < 4; ++c) o_[g][c] = (f32x4){0.f, 0.f, 0.f, 0.f};
  float m_s[2] = {-1e30f, -1e30f};
  float l_s[2] = {0.f, 0.f};

  // staging geometry (swizzled gld16): wave w covers rows w*16..w*16+15
  const int gr = lane >> 3;
  const int kcs = (((lane & 7) ^ gr) << 3);  // swizzled granule (ushorts)
  const int s7 = col & 7;
  const ushort* krowp = K + base + (size_t)(w * 16 + gr) * 1024 + kcs;
  const ushort* vrowp =
      VT + (size_t)(h * 64 + w * 16 + gr) * 8192 + (size_t)b * 1024 + kcs;

  auto stageKV = [&](ushort* kb, ushort* vb, int kt) {
    const ushort* k0 = krowp + (size_t)kt * 64 * 1024;
    gld16(k0, kb + (w * 16) * 64);
    gld16(k0 + (size_t)8 * 1024, kb + (w * 16 + 8) * 64);
    const ushort* v0 = vrowp + kt * 64;
    gld16(v0, vb + (w * 16) * 64);
    gld16(v0 + (size_t)8 * 8192, vb + (w * 16 + 8) * 64);
  };

  auto body = [&](const ushort* kb, const ushort* vb) {
    // S^T = K Q^T; sc[g][c][r] = S[q=lane&15(+g*16+w*32)][k=c*16+quad*4+r]
    f32x4 sc[2][4];
    __builtin_amdgcn_s_setprio(1);
#pragma unroll
    for (int c = 0; c < 4; ++c) {
      const int R = (c * 16 + col) * 64;
      bf16x8 kb0 = ld8(&kb[R + ((quad ^ s7) << 3)]);
      bf16x8 kb1 = ld8(&kb[R + (((quad + 4) ^ s7) << 3)]);
#pragma unroll
      for (int g = 0; g < 2; ++g) {
        f32x4 z = {0.f, 0.f, 0.f, 0.f};
        z = __builtin_amdgcn_mfma_f32_16x16x32_bf16(kb0, qa[g][0], z, 0, 0, 0);
        z = __builtin_amdgcn_mfma_f32_16x16x32_bf16(kb1, qa[g][1], z, 0, 0, 0);
        sc[g][c] = z;
      }
    }
    __builtin_amdgcn_s_setprio(0);

    // online softmax, row-local, with defer-max (THR=8)
    float al[2];
    bool df[2];
#pragma unroll
    for (int g = 0; g < 2; ++g) {
      float mx = sc[g][0][0];
#pragma unroll
      for (int c = 0; c < 4; ++c)
#pragma unroll
        for (int r = 0; r < 4; ++r) mx = fmaxf(mx, sc[g][c][r]);
      mx = fmaxf(mx, __shfl_xor(mx, 16));
      mx = fmaxf(mx, __shfl_xor(mx, 32));
      df[g] = __all(mx - m_s[g] <= 8.0f) != 0;
      if (df[g]) {
        al[g] = 1.0f;
      } else {
        const float m_new = fmaxf(m_s[g], mx);
        al[g] = __expf(m_s[g] - m_new);
        m_s[g] = m_new;
      }
      float rs = 0.f;
      const int prow = (w * 32 + g * 16 + col) * 72;
#pragma unroll
      for (int c = 0; c < 4; ++c) {
        const float p0 = __expf(sc[g][c][0] - m_s[g]);
        const float p1 = __expf(sc[g][c][1] - m_s[g]);
        const float p2 = __expf(sc[g][c][2] - m_s[g]);
        const float p3 = __expf(sc[g][c][3] - m_s[g]);
        rs += (p0 + p1) + (p2 + p3);
        union { uint2 u; ushort s[4]; } pk;
        pk.s[0] = f2bf(p0);
        pk.s[1] = f2bf(p1);
        pk.s[2] = f2bf(p2);
        pk.s[3] = f2bf(p3);
        *reinterpret_cast<uint2*>(&QP[prow + c * 16 + quad * 4]) = pk.u;
      }
      rs += __shfl_xor(rs, 16);
      rs += __shfl_xor(rs, 32);
      l_s[g] = df[g] ? (l_s[g] + rs) : (l_s[g] * al[g] + rs);
    }

    // rescale O with per-row alpha (skipped entirely when deferred)
#pragma unroll
    for (int g = 0; g < 2; ++g)
      if (!df[g]) {
#pragma unroll
        for (int r = 0; r < 4; ++r) {
          const float a = __shfl(al[g], (lane & 48) | (quad * 4 + r));
          o_[g][0][r] *= a;
          o_[g][1][r] *= a;
          o_[g][2][r] *= a;
          o_[g][3][r] *= a;
        }
      }

    // O += P V (own-wave P rows; in-wave DS order suffices)
    bf16x8 pa[2][2];
#pragma unroll
    for (int g = 0; g < 2; ++g)
#pragma unroll
      for (int half = 0; half < 2; ++half)
        pa[g][half] =
            ld8(&QP[(w * 32 + g * 16 + col) * 72 + half * 32 + quad * 8]);
    __builtin_amdgcn_s_setprio(1);
#pragma unroll
    for (int c = 0; c < 4; ++c) {
      const int R = (c * 16 + col) * 64;
      bf16x8 vb0 = ld8(&vb[R + ((quad ^ s7) << 3)]);
      bf16x8 vb1 = ld8(&vb[R + (((quad + 4) ^ s7) << 3)]);
#pragma unroll
      for (int g = 0; g < 2; ++g) {
        o_[g][c] = __builtin_amdgcn_mfma_f32_16x16x32_bf16(pa[g][0], vb0,
                                                           o_[g][c], 0, 0, 0);
        o_[g][c] = __builtin_amdgcn_mfma_f32_16x16x32_bf16(pa[g][1], vb1,
                                                           o_[g][c], 0, 0, 0);
      }
    }
    __builtin_amdgcn_s_setprio(0);
  };

  // prologue: stage tile 0, full drain (also completes qa reads before any
  // wave can write P into QP -> race-free)
  stageKV(Ks0, Vt0, 0);
  __syncthreads();

  for (int t2 = 0; t2 < 16; t2 += 2) {
    // even step: compute buf0, stage t2+1 -> buf1 (t2+1 <= 15 always)
    stageKV(Ks1, Vt1, t2 + 1);
    asm volatile("s_waitcnt vmcnt(4)" ::: "memory");
    __builtin_amdgcn_sched_barrier(0);
    __builtin_amdgcn_s_barrier();
    __builtin_amdgcn_sched_barrier(0);
    body(Ks0, Vt0);
    asm volatile("s_waitcnt lgkmcnt(0)" ::: "memory");
    __builtin_amdgcn_sched_barrier(0);
    __builtin_amdgcn_s_barrier();

    // odd step: compute buf1, stage t2+2 -> buf0 (skip on last)
    if (t2 < 14) {
      stageKV(Ks0, Vt0, t2 + 2);
      asm volatile("s_waitcnt vmcnt(4)" ::: "memory");
    } else {
      asm volatile("s_waitcnt vmcnt(0)" ::: "memory");
    }
    __builtin_amdgcn_sched_barrier(0);
    __builtin_amdgcn_s_barrier();
    __builtin_amdgcn_sched_barrier(0);
    body(Ks1, Vt1);
    asm volatile("s_waitcnt lgkmcnt(0)" ::: "memory");
    __builtin_amdgcn_sched_barrier(0);
    __builtin_amdgcn_s_barrier();
  }

#pragma unroll
  for (int g = 0; g < 2; ++g)
#pragma unroll
    for (int r = 0; r < 4; ++r) {
      const float lr = __shfl(l_s[g], (lane & 48) | (quad * 4 + r));
      const float inv = 1.f / lr;
      const size_t row =
          base + (size_t)(qrow0 + w * 32 + g * 16 + quad * 4 + r) * 1024;
      O[row + 0 + col] = f2bf(o_[g][0][r] * inv);
      O[row + 16 + col] = f2bf(o_[g][1][r] * inv);
      O[row + 32 + col] = f2bf(o_[g][2][r] * inv);
      O[row + 48 + col] = f2bf(o_[g][3][r] * inv);
    }
}

// --------------------------------------------------------------------------
extern "C" void kernel_launch(void* const* d_in, const int* in_sizes, int n_in,
                              void* d_out, int out_size, void* d_ws, size_t ws_size,
                              hipStream_t stream) {
  const float* q = (const float*)d_in[0];
  const float* k = (const float*)d_in[1];
  const float* v = (const float*)d_in[2];
  const float* Wq = (const float*)d_in[3];
  const float* Wk = (const float*)d_in[4];
  const float* Wv = (const float*)d_in[5];
  const float* Wo = (const float*)d_in[6];
  const float* bo = (const float*)d_in[7];
  float* out = (float*)d_out;
  ushort* ws = (ushort*)d_ws;

  const size_t M8 = 8u << 20;  // 8M bf16 = 16 MB
  const size_t M1 = 1u << 20;
  ushort* Qp = ws;                 // also flash output (in-place)
  ushort* Kp = ws + M8;
  ushort* VpT = ws + 2 * M8;       // V TRANSPOSED [1024][8192]
  ushort* WqT = ws + 3 * M8;
  ushort* WkT = WqT + M1;
  ushort* WvT = WkT + M1;
  ushort* WoB = WvT + M1;          // total 56 MB

  // d_out (32 MB fp32) as bf16 scratch: q~ at 0, k~ at +16MB.
  ushort* X0 = (ushort*)d_out;
  ushort* X1 = X0 + M8;

  prep_wt3<<<768, 256, 0, stream>>>(Wq, Wk, Wv, WqT, WkT, WvT);
  cvt3<<<4352, 256, 0, stream>>>(q, X0, k, X1, Wo, WoB);
  // attn scale folded into Q projection (exact: 2^-5 exponent shift in bf16)
  gemm_proj3<<<1536, 256, 0, stream>>>(X0, WqT, Qp, X1, WkT, Kp, v, WvT, VpT);

  flash_attn<<<1024, 256, 0, stream>>>(Qp, Kp, VpT, Qp);

  gemm_out<<<1024, 256, 0, stream>>>(Qp, WoB, bo, out);
}